// Round 7
// baseline (392.278 us; speedup 1.0000x reference)
//
#include <hip/hip_runtime.h>

#define N_TOK 8192
#define DDIM 1024
#define ODIM 1024
#define NEXP 8

typedef __attribute__((ext_vector_type(8))) short bf16x8;
typedef __attribute__((ext_vector_type(4))) float f32x4;

__device__ __forceinline__ unsigned int f2bf(float f) {
    unsigned int u = __float_as_uint(f);
    return (u + 0x7fffu + ((u >> 16) & 1u)) >> 16;  // RNE
}

__device__ __forceinline__ void async_copy16(const unsigned short* g, unsigned short* l) {
    __builtin_amdgcn_global_load_lds(
        (const __attribute__((address_space(1))) unsigned int*)g,
        (__attribute__((address_space(3))) unsigned int*)l, 16, 0, 0);
}

// ---------------- fused prep: gate+out-zero (blocks 0..2047) + We transpose (2048..4095) ----
__global__ __launch_bounds__(256) void prep_kernel(const float* __restrict__ x,
                                                   const float* __restrict__ Wg,
                                                   const float* __restrict__ bg,
                                                   const float* __restrict__ We,
                                                   int* __restrict__ ea, int* __restrict__ eb,
                                                   float* __restrict__ ga, float* __restrict__ gb,
                                                   unsigned short* __restrict__ xbf,
                                                   unsigned short* __restrict__ WeT,
                                                   int* __restrict__ counts,
                                                   float* __restrict__ out) {
    __shared__ float tile[64][65];
    if (blockIdx.x < 2048) {
        // ---- gate: one token per wave; emits x as bf16; zeroes counts and out rows ----
        if (blockIdx.x == 0) counts[threadIdx.x] = 0;  // 8*32 padded counters
        const int wave = threadIdx.x >> 6, lane = threadIdx.x & 63;
        const int t = blockIdx.x * 4 + wave;
        const float* xr = x + (size_t)t * DDIM;

        // zero this token's output row (gemm accumulates into it atomically)
        float* orow = out + ((size_t)t << 10);
        const float4 z = {0.f, 0.f, 0.f, 0.f};
#pragma unroll
        for (int c = 0; c < 4; ++c) *(float4*)&orow[c * 256 + lane * 4] = z;

        float4 v[4];
#pragma unroll
        for (int c = 0; c < 4; ++c) v[c] = *(const float4*)&xr[c * 256 + lane * 4];

        unsigned short* xo = xbf + (size_t)t * DDIM;
#pragma unroll
        for (int c = 0; c < 4; ++c) {
            uint2 w;
            w.x = f2bf(v[c].x) | (f2bf(v[c].y) << 16);
            w.y = f2bf(v[c].z) | (f2bf(v[c].w) << 16);
            *(uint2*)&xo[c * 256 + lane * 4] = w;
        }

        float acc[8] = {0, 0, 0, 0, 0, 0, 0, 0};
#pragma unroll
        for (int c = 0; c < 4; ++c) {
            const int dbase = c * 256 + lane * 4;
#pragma unroll
            for (int j = 0; j < 4; ++j) {
                float xv = ((const float*)&v[c])[j];
                const float4* w = (const float4*)(Wg + (size_t)(dbase + j) * 8);
                float4 w0 = w[0], w1 = w[1];
                acc[0] += xv * w0.x; acc[1] += xv * w0.y; acc[2] += xv * w0.z; acc[3] += xv * w0.w;
                acc[4] += xv * w1.x; acc[5] += xv * w1.y; acc[6] += xv * w1.z; acc[7] += xv * w1.w;
            }
        }
#pragma unroll
        for (int off = 32; off > 0; off >>= 1) {
#pragma unroll
            for (int j = 0; j < 8; ++j) acc[j] += __shfl_xor(acc[j], off, 64);
        }
        if (lane == 0) {
            float s[8];
#pragma unroll
            for (int e = 0; e < 8; ++e) s[e] = acc[e] + bg[e];
            int a = 0;
#pragma unroll
            for (int e = 1; e < 8; ++e) if (s[e] > s[a]) a = e;
            int b = (a == 0) ? 1 : 0;
#pragma unroll
            for (int e = 0; e < 8; ++e) if (e != a && e != b && s[e] > s[b]) b = e;
            float g0 = 1.0f / (1.0f + __expf(s[b] - s[a]));  // renormed top-2 softmax
            ea[t] = a; eb[t] = b; ga[t] = g0; gb[t] = 1.0f - g0;
        }
    } else {
        // ---- We [E,D,O] fp32 -> WeT [E,O,D] bf16, 64x64 tiles ----
        const int lin = blockIdx.x - 2048;
        const int e = lin >> 8, rem = lin & 255;
        const int d0 = (rem >> 4) * 64, o0 = (rem & 15) * 64;
        const int tid = threadIdx.x;
#pragma unroll
        for (int p = 0; p < 4; ++p) {
            int idx = p * 256 + tid;
            int row = idx >> 4, c = idx & 15;
            float4 v = *(const float4*)&We[(((size_t)e * 1024 + d0 + row) << 10) + o0 + (c << 2)];
            tile[row][c * 4 + 0] = v.x; tile[row][c * 4 + 1] = v.y;
            tile[row][c * 4 + 2] = v.z; tile[row][c * 4 + 3] = v.w;
        }
        __syncthreads();
#pragma unroll
        for (int p = 0; p < 2; ++p) {
            int idx = p * 256 + tid;
            int orow = idx >> 3, c8 = idx & 7;
            unsigned int u[8];
#pragma unroll
            for (int j = 0; j < 8; ++j) u[j] = f2bf(tile[c8 * 8 + j][orow]);
            uint4 q;
            q.x = u[0] | (u[1] << 16); q.y = u[2] | (u[3] << 16);
            q.z = u[4] | (u[5] << 16); q.w = u[6] | (u[7] << 16);
            *(uint4*)&WeT[(((size_t)e * 1024 + o0 + orow) << 10) + d0 + (c8 << 3)] = q;
        }
    }
}

// ---------------- bucket scatter: wave-ballot aggregation; emits btok + per-slot weight ----
__global__ __launch_bounds__(64) void scatter_kernel(const int* __restrict__ ea,
                                                     const int* __restrict__ eb,
                                                     const float* __restrict__ ga,
                                                     const float* __restrict__ gb,
                                                     int* __restrict__ counts,
                                                     int* __restrict__ btok,
                                                     float* __restrict__ wtok) {
    const int t = blockIdx.x * 64 + threadIdx.x;  // grid = 128 blocks x 1 wave
    const int lane = threadIdx.x & 63;
#pragma unroll
    for (int pass = 0; pass < 2; ++pass) {
        const int e = (pass == 0) ? ea[t] : eb[t];
        const float wg = (pass == 0) ? ga[t] : gb[t];
#pragma unroll
        for (int ex = 0; ex < NEXP; ++ex) {
            unsigned long long mask = __ballot(e == ex);
            if (mask) {
                int leader = __ffsll((long long)mask) - 1;
                int base = 0;
                if (lane == leader) base = atomicAdd(&counts[ex * 32], __popcll(mask));
                base = __shfl(base, leader, 64);
                if (e == ex) {
                    int pos = base + __popcll(mask & ((1ull << lane) - 1ull));
                    btok[ex * N_TOK + pos] = t;
                    wtok[ex * N_TOK + pos] = wg;
                }
            }
        }
    }
}

// ---------------- grouped expert GEMM, 160x128 tile, BK=64, counted-vmcnt pipeline ----------
// R5 main loop verbatim (best measured: 60.5 us). Epilogue fused with combine: per valid
// row, out[token] += w * (acc + bias) via fp32 HW atomics (each out element receives
// exactly 2 adds, one per selected expert; out pre-zeroed by prep). Kills the separate
// combine kernel, ybuf (32 MB writes) and its 67 MB of traffic.
__global__ __launch_bounds__(256, 2) void moe_gemm(const unsigned short* __restrict__ xbf,
                                                   const unsigned short* __restrict__ WeT,
                                                   const float* __restrict__ be,
                                                   const int* __restrict__ counts,
                                                   const int* __restrict__ btok,
                                                   const float* __restrict__ wtok,
                                                   float* __restrict__ out) {
    const int id = blockIdx.x;
    const int e = id & 7;                     // expert -> XCD pinning (id%8 round-robin)
    const int n0 = ((id >> 3) & 7) * 128;     // 8 n-tiles share one A-tile, same XCD
    const int r0 = (id >> 6) * 160;
    const int cnt = counts[e * 32];
    if (r0 >= cnt) return;

    // LDS: A0[160x64] A1[160x64] B0[128x64] B1[128x64] (shorts)
    __shared__ unsigned short smem[36864];    // 73728 B
    __shared__ int s_tok[160];

    const int tid = threadIdx.x;
    if (tid < 160) {
        int r = r0 + tid;
        int rc = (r < cnt) ? r : (cnt - 1);
        s_tok[tid] = btok[e * N_TOK + rc];
    }
    const int w = tid >> 6, lane = tid & 63;
    __syncthreads();

    // staging: pass p covers rows p*32 + w*8 + rsub; global chunk (lane&7)^rsub (XOR swizzle)
    const int rsub = lane >> 3;
    const int colo = ((lane & 7) ^ rsub) * 8;
    unsigned int a_off[5], b_off[4];
#pragma unroll
    for (int p = 0; p < 5; ++p) {
        int row = p * 32 + w * 8 + rsub;
        a_off[p] = ((unsigned)s_tok[row] << 10) + colo;
    }
#pragma unroll
    for (int p = 0; p < 4; ++p) {
        int row = p * 32 + w * 8 + rsub;
        b_off[p] = ((unsigned)(e * 1024 + n0 + row) << 10) + colo;
    }
    const int ldsrow = w * 8;  // wave-uniform LDS row base within each 32-row pass

    const int wm = (w >> 1) * 80, wn = (w & 1) * 64;
    const int quad = lane >> 4, rA = lane & 15;
    const int sw = rA & 7;
    const int cs0 = (quad ^ sw) * 8;        // ks=0 swizzled chunk (elems)
    const int cs1 = ((4 + quad) ^ sw) * 8;  // ks=1

    f32x4 acc[5][4];
#pragma unroll
    for (int mi = 0; mi < 5; ++mi)
#pragma unroll
        for (int ni = 0; ni < 4; ++ni) acc[mi][ni] = (f32x4){0.f, 0.f, 0.f, 0.f};

    // LDS short-offsets: A0=0, A1=10240, B0=20480, B1=28672
    // prologue: stage tile 0 -> buf0, tile 1 -> buf1; wait tile0 (9 of 18 outstanding)
#pragma unroll
    for (int p = 0; p < 5; ++p)
        async_copy16(xbf + a_off[p], &smem[(p * 32 + ldsrow) * 64]);
#pragma unroll
    for (int p = 0; p < 4; ++p)
        async_copy16(WeT + b_off[p], &smem[20480 + (p * 32 + ldsrow) * 64]);
#pragma unroll
    for (int p = 0; p < 5; ++p)
        async_copy16(xbf + a_off[p] + 64, &smem[10240 + (p * 32 + ldsrow) * 64]);
#pragma unroll
    for (int p = 0; p < 4; ++p)
        async_copy16(WeT + b_off[p] + 64, &smem[28672 + (p * 32 + ldsrow) * 64]);
    asm volatile("s_waitcnt vmcnt(9)" ::: "memory");
    __builtin_amdgcn_s_barrier();
    __builtin_amdgcn_sched_barrier(0);

    // pre-issue F0 = (tile 0, ks0)
    bf16x8 a0[5], b0[4];
#pragma unroll
    for (int i = 0; i < 5; ++i) a0[i] = *(bf16x8*)&smem[(wm + i * 16 + rA) * 64 + cs0];
#pragma unroll
    for (int i = 0; i < 4; ++i) b0[i] = *(bf16x8*)&smem[20480 + (wn + i * 16 + rA) * 64 + cs0];

    for (int t = 0; t < 16; ++t) {
        const int cur = t & 1;
        unsigned short* sAc = smem + cur * 10240;
        unsigned short* sBc = smem + 20480 + cur * 8192;
        unsigned short* sAn = smem + (cur ^ 1) * 10240;
        unsigned short* sBn = smem + 20480 + (cur ^ 1) * 8192;

        // issue F1 = (t, ks1) reads; MFMA(F0) overlaps their latency
        bf16x8 a1[5], b1[4];
#pragma unroll
        for (int i = 0; i < 5; ++i) a1[i] = *(bf16x8*)&sAc[(wm + i * 16 + rA) * 64 + cs1];
#pragma unroll
        for (int i = 0; i < 4; ++i) b1[i] = *(bf16x8*)&sBc[(wn + i * 16 + rA) * 64 + cs1];
        __builtin_amdgcn_s_setprio(1);
#pragma unroll
        for (int mi = 0; mi < 5; ++mi)
#pragma unroll
            for (int ni = 0; ni < 4; ++ni)
                acc[mi][ni] = __builtin_amdgcn_mfma_f32_16x16x32_bf16(b0[ni], a0[mi], acc[mi][ni], 0, 0, 0);
        __builtin_amdgcn_s_setprio(0);

        // drain this wave's reads of buf[cur], then free it for re-staging
        asm volatile("s_waitcnt lgkmcnt(0)" ::: "memory");
        __builtin_amdgcn_sched_barrier(0);
        __builtin_amdgcn_s_barrier();
        __builtin_amdgcn_sched_barrier(0);

        if (t < 14) {
            const int ko = (t + 2) * 64;
#pragma unroll
            for (int p = 0; p < 5; ++p)
                async_copy16(xbf + a_off[p] + ko, &sAc[(p * 32 + ldsrow) * 64]);
#pragma unroll
            for (int p = 0; p < 4; ++p)
                async_copy16(WeT + b_off[p] + ko, &sBc[(p * 32 + ldsrow) * 64]);
        }
        if (t < 15) {
            if (t < 14) {
                asm volatile("s_waitcnt vmcnt(9)" ::: "memory");  // t+1 landed; t+2 in flight
            } else {
                asm volatile("s_waitcnt vmcnt(0)" ::: "memory");  // tile 15 landed
            }
            __builtin_amdgcn_sched_barrier(0);
            __builtin_amdgcn_s_barrier();
            __builtin_amdgcn_sched_barrier(0);
            // issue F0' = (t+1, ks0) reads; MFMA(F1) below overlaps their latency
#pragma unroll
            for (int i = 0; i < 5; ++i) a0[i] = *(bf16x8*)&sAn[(wm + i * 16 + rA) * 64 + cs0];
#pragma unroll
            for (int i = 0; i < 4; ++i) b0[i] = *(bf16x8*)&sBn[(wn + i * 16 + rA) * 64 + cs0];
        }

        __builtin_amdgcn_s_setprio(1);
#pragma unroll
        for (int mi = 0; mi < 5; ++mi)
#pragma unroll
            for (int ni = 0; ni < 4; ++ni)
                acc[mi][ni] = __builtin_amdgcn_mfma_f32_16x16x32_bf16(b1[ni], a1[mi], acc[mi][ni], 0, 0, 0);
        __builtin_amdgcn_s_setprio(0);
    }

    // fused epilogue: swapped-operand D layout -> lane (quad,rA) holds rows wm+mi*16+rA,
    // cols wn+ni*16+quad*4..+3. out[token] += w*(acc+bias), fp32 HW atomic (no return).
    float4 bv[4];
#pragma unroll
    for (int ni = 0; ni < 4; ++ni)
        bv[ni] = *(const float4*)&be[(e << 10) + n0 + wn + ni * 16 + quad * 4];
#pragma unroll
    for (int mi = 0; mi < 5; ++mi) {
        const int lrow = wm + mi * 16 + rA;
        if (r0 + lrow < cnt) {
            const int tok = s_tok[lrow];
            const float wgt = wtok[e * N_TOK + r0 + lrow];
            float* orow = out + ((size_t)tok << 10) + n0 + wn + quad * 4;
#pragma unroll
            for (int ni = 0; ni < 4; ++ni) {
                unsafeAtomicAdd(&orow[ni * 16 + 0], wgt * (acc[mi][ni][0] + bv[ni].x));
                unsafeAtomicAdd(&orow[ni * 16 + 1], wgt * (acc[mi][ni][1] + bv[ni].y));
                unsafeAtomicAdd(&orow[ni * 16 + 2], wgt * (acc[mi][ni][2] + bv[ni].z));
                unsafeAtomicAdd(&orow[ni * 16 + 3], wgt * (acc[mi][ni][3] + bv[ni].w));
            }
        }
    }
}

extern "C" void kernel_launch(void* const* d_in, const int* in_sizes, int n_in,
                              void* d_out, int out_size, void* d_ws, size_t ws_size,
                              hipStream_t stream) {
    const float* x  = (const float*)d_in[0];
    const float* We = (const float*)d_in[1];
    const float* be = (const float*)d_in[2];
    const float* Wg = (const float*)d_in[3];
    const float* bg = (const float*)d_in[4];
    float* out = (float*)d_out;

    char* ws = (char*)d_ws;
    size_t off = 0;
    int* counts = (int*)(ws + off); off += 8 * 32 * 4;            // 1 KB, padded 128 B/counter
    int* btok   = (int*)(ws + off); off += NEXP * N_TOK * 4;      // 256 KB
    float* wtok = (float*)(ws + off); off += NEXP * N_TOK * 4;    // 256 KB
    int* ea = (int*)(ws + off); off += N_TOK * 4;
    int* eb = (int*)(ws + off); off += N_TOK * 4;
    float* ga = (float*)(ws + off); off += N_TOK * 4;
    float* gb = (float*)(ws + off); off += N_TOK * 4;
    unsigned short* WeT  = (unsigned short*)(ws + off); off += (size_t)NEXP * DDIM * ODIM * 2;  // 16.78 MB
    unsigned short* xbf  = (unsigned short*)(ws + off); off += (size_t)N_TOK * DDIM * 2;        // 16.78 MB

    prep_kernel<<<dim3(4096), 256, 0, stream>>>(x, Wg, bg, We, ea, eb, ga, gb, xbf, WeT, counts, out);
    scatter_kernel<<<dim3(N_TOK / 64), 64, 0, stream>>>(ea, eb, ga, gb, counts, btok, wtok);
    moe_gemm<<<dim3(64 * 8 * 8), 256, 0, stream>>>(xbf, WeT, be, counts, btok, wtok, out);
}

// Round 9
// 202.954 us; speedup vs baseline: 1.9328x; 1.9328x over previous
//
#include <hip/hip_runtime.h>

#define N_TOK 8192
#define DDIM 1024
#define ODIM 1024
#define NEXP 8

typedef __attribute__((ext_vector_type(8))) short bf16x8;
typedef __attribute__((ext_vector_type(4))) float f32x4;

__device__ __forceinline__ unsigned int f2bf(float f) {
    unsigned int u = __float_as_uint(f);
    return (u + 0x7fffu + ((u >> 16) & 1u)) >> 16;  // RNE
}
__device__ __forceinline__ float bflo(unsigned int u) { return __uint_as_float(u << 16); }
__device__ __forceinline__ float bfhi(unsigned int u) { return __uint_as_float(u & 0xffff0000u); }

__device__ __forceinline__ void async_copy16(const unsigned short* g, unsigned short* l) {
    __builtin_amdgcn_global_load_lds(
        (const __attribute__((address_space(1))) unsigned int*)g,
        (__attribute__((address_space(3))) unsigned int*)l, 16, 0, 0);
}

// ---------------- fused prep: gate (blocks 0..2047) + We transpose (blocks 2048..4095) ----------
// Block 0 zeroes the padded counters; all counter atomics happen in the NEXT kernel
// (scatter), so there is no zero-vs-increment race. No runtime API calls needed.
__global__ __launch_bounds__(256) void prep_kernel(const float* __restrict__ x,
                                                   const float* __restrict__ Wg,
                                                   const float* __restrict__ bg,
                                                   const float* __restrict__ We,
                                                   int* __restrict__ ea, int* __restrict__ eb,
                                                   float* __restrict__ ga, float* __restrict__ gb,
                                                   unsigned short* __restrict__ xbf,
                                                   unsigned short* __restrict__ WeT,
                                                   int* __restrict__ counts) {
    __shared__ float tile[64][65];
    if (blockIdx.x < 2048) {
        // ---- gate: one token per wave; emits x as bf16; zeroes counts ----
        if (blockIdx.x == 0) counts[threadIdx.x] = 0;  // 8*32 padded counters
        const int wave = threadIdx.x >> 6, lane = threadIdx.x & 63;
        const int t = blockIdx.x * 4 + wave;
        const float* xr = x + (size_t)t * DDIM;

        float4 v[4];
#pragma unroll
        for (int c = 0; c < 4; ++c) v[c] = *(const float4*)&xr[c * 256 + lane * 4];

        unsigned short* xo = xbf + (size_t)t * DDIM;
#pragma unroll
        for (int c = 0; c < 4; ++c) {
            uint2 w;
            w.x = f2bf(v[c].x) | (f2bf(v[c].y) << 16);
            w.y = f2bf(v[c].z) | (f2bf(v[c].w) << 16);
            *(uint2*)&xo[c * 256 + lane * 4] = w;
        }

        float acc[8] = {0, 0, 0, 0, 0, 0, 0, 0};
#pragma unroll
        for (int c = 0; c < 4; ++c) {
            const int dbase = c * 256 + lane * 4;
#pragma unroll
            for (int j = 0; j < 4; ++j) {
                float xv = ((const float*)&v[c])[j];
                const float4* w = (const float4*)(Wg + (size_t)(dbase + j) * 8);
                float4 w0 = w[0], w1 = w[1];
                acc[0] += xv * w0.x; acc[1] += xv * w0.y; acc[2] += xv * w0.z; acc[3] += xv * w0.w;
                acc[4] += xv * w1.x; acc[5] += xv * w1.y; acc[6] += xv * w1.z; acc[7] += xv * w1.w;
            }
        }
#pragma unroll
        for (int off = 32; off > 0; off >>= 1) {
#pragma unroll
            for (int j = 0; j < 8; ++j) acc[j] += __shfl_xor(acc[j], off, 64);
        }
        if (lane == 0) {
            float s[8];
#pragma unroll
            for (int e = 0; e < 8; ++e) s[e] = acc[e] + bg[e];
            int a = 0;
#pragma unroll
            for (int e = 1; e < 8; ++e) if (s[e] > s[a]) a = e;
            int b = (a == 0) ? 1 : 0;
#pragma unroll
            for (int e = 0; e < 8; ++e) if (e != a && e != b && s[e] > s[b]) b = e;
            float g0 = 1.0f / (1.0f + __expf(s[b] - s[a]));  // renormed top-2 softmax
            ea[t] = a; eb[t] = b; ga[t] = g0; gb[t] = 1.0f - g0;
        }
    } else {
        // ---- We [E,D,O] fp32 -> WeT [E,O,D] bf16, 64x64 tiles ----
        const int lin = blockIdx.x - 2048;
        const int e = lin >> 8, rem = lin & 255;
        const int d0 = (rem >> 4) * 64, o0 = (rem & 15) * 64;
        const int tid = threadIdx.x;
#pragma unroll
        for (int p = 0; p < 4; ++p) {
            int idx = p * 256 + tid;
            int row = idx >> 4, c = idx & 15;
            float4 v = *(const float4*)&We[(((size_t)e * 1024 + d0 + row) << 10) + o0 + (c << 2)];
            tile[row][c * 4 + 0] = v.x; tile[row][c * 4 + 1] = v.y;
            tile[row][c * 4 + 2] = v.z; tile[row][c * 4 + 3] = v.w;
        }
        __syncthreads();
#pragma unroll
        for (int p = 0; p < 2; ++p) {
            int idx = p * 256 + tid;
            int orow = idx >> 3, c8 = idx & 7;
            unsigned int u[8];
#pragma unroll
            for (int j = 0; j < 8; ++j) u[j] = f2bf(tile[c8 * 8 + j][orow]);
            uint4 q;
            q.x = u[0] | (u[1] << 16); q.y = u[2] | (u[3] << 16);
            q.z = u[4] | (u[5] << 16); q.w = u[6] | (u[7] << 16);
            *(uint4*)&WeT[(((size_t)e * 1024 + o0 + orow) << 10) + d0 + (c8 << 3)] = q;
        }
    }
}

// ---------------- bucket scatter: wave-ballot aggregation; records slots ----------------
__global__ __launch_bounds__(64) void scatter_kernel(const int* __restrict__ ea,
                                                     const int* __restrict__ eb,
                                                     int* __restrict__ counts,
                                                     int* __restrict__ btok,
                                                     int* __restrict__ slotA,
                                                     int* __restrict__ slotB) {
    const int t = blockIdx.x * 64 + threadIdx.x;  // grid = 128 blocks x 1 wave
    const int lane = threadIdx.x & 63;
#pragma unroll
    for (int pass = 0; pass < 2; ++pass) {
        const int e = (pass == 0) ? ea[t] : eb[t];
        int* slot = (pass == 0) ? slotA : slotB;
#pragma unroll
        for (int ex = 0; ex < NEXP; ++ex) {
            unsigned long long mask = __ballot(e == ex);
            if (mask) {
                int leader = __ffsll((long long)mask) - 1;
                int base = 0;
                if (lane == leader) base = atomicAdd(&counts[ex * 32], __popcll(mask));
                base = __shfl(base, leader, 64);
                if (e == ex) {
                    int pos = base + __popcll(mask & ((1ull << lane) - 1ull));
                    btok[ex * N_TOK + pos] = t;
                    slot[t] = ex * N_TOK + pos;
                }
            }
        }
    }
}

// ---------------- grouped expert GEMM, 160x128 tile, BK=64, counted-vmcnt pipeline ----------
// R5 main loop verbatim (best measured: 60.5 us, MfmaUtil ~23, 0 LDS conflicts).
__global__ __launch_bounds__(256, 2) void moe_gemm(const unsigned short* __restrict__ xbf,
                                                   const unsigned short* __restrict__ WeT,
                                                   const float* __restrict__ be,
                                                   const int* __restrict__ counts,
                                                   const int* __restrict__ btok,
                                                   unsigned short* __restrict__ ybuf) {
    const int id = blockIdx.x;
    const int e = id & 7;                     // expert -> XCD pinning (id%8 round-robin)
    const int n0 = ((id >> 3) & 7) * 128;     // 8 n-tiles share one A-tile, same XCD
    const int r0 = (id >> 6) * 160;
    const int cnt = counts[e * 32];
    if (r0 >= cnt) return;

    // LDS: A0[160x64] A1[160x64] B0[128x64] B1[128x64] (shorts)
    __shared__ unsigned short smem[36864];    // 73728 B
    __shared__ int s_tok[160];

    const int tid = threadIdx.x;
    if (tid < 160) {
        int r = r0 + tid;
        int rc = (r < cnt) ? r : (cnt - 1);
        s_tok[tid] = btok[e * N_TOK + rc];
    }
    const int w = tid >> 6, lane = tid & 63;
    __syncthreads();

    // staging: pass p covers rows p*32 + w*8 + rsub; global chunk (lane&7)^rsub (XOR swizzle)
    const int rsub = lane >> 3;
    const int colo = ((lane & 7) ^ rsub) * 8;
    unsigned int a_off[5], b_off[4];
#pragma unroll
    for (int p = 0; p < 5; ++p) {
        int row = p * 32 + w * 8 + rsub;
        a_off[p] = ((unsigned)s_tok[row] << 10) + colo;
    }
#pragma unroll
    for (int p = 0; p < 4; ++p) {
        int row = p * 32 + w * 8 + rsub;
        b_off[p] = ((unsigned)(e * 1024 + n0 + row) << 10) + colo;
    }
    const int ldsrow = w * 8;  // wave-uniform LDS row base within each 32-row pass

    const int wm = (w >> 1) * 80, wn = (w & 1) * 64;
    const int quad = lane >> 4, rA = lane & 15;
    const int sw = rA & 7;
    const int cs0 = (quad ^ sw) * 8;        // ks=0 swizzled chunk (elems)
    const int cs1 = ((4 + quad) ^ sw) * 8;  // ks=1

    f32x4 acc[5][4];
#pragma unroll
    for (int mi = 0; mi < 5; ++mi)
#pragma unroll
        for (int ni = 0; ni < 4; ++ni) acc[mi][ni] = (f32x4){0.f, 0.f, 0.f, 0.f};

    // LDS short-offsets: A0=0, A1=10240, B0=20480, B1=28672
    // prologue: stage tile 0 -> buf0, tile 1 -> buf1; wait tile0 (9 of 18 outstanding)
#pragma unroll
    for (int p = 0; p < 5; ++p)
        async_copy16(xbf + a_off[p], &smem[(p * 32 + ldsrow) * 64]);
#pragma unroll
    for (int p = 0; p < 4; ++p)
        async_copy16(WeT + b_off[p], &smem[20480 + (p * 32 + ldsrow) * 64]);
#pragma unroll
    for (int p = 0; p < 5; ++p)
        async_copy16(xbf + a_off[p] + 64, &smem[10240 + (p * 32 + ldsrow) * 64]);
#pragma unroll
    for (int p = 0; p < 4; ++p)
        async_copy16(WeT + b_off[p] + 64, &smem[28672 + (p * 32 + ldsrow) * 64]);
    asm volatile("s_waitcnt vmcnt(9)" ::: "memory");
    __builtin_amdgcn_s_barrier();
    __builtin_amdgcn_sched_barrier(0);

    // pre-issue F0 = (tile 0, ks0)
    bf16x8 a0[5], b0[4];
#pragma unroll
    for (int i = 0; i < 5; ++i) a0[i] = *(bf16x8*)&smem[(wm + i * 16 + rA) * 64 + cs0];
#pragma unroll
    for (int i = 0; i < 4; ++i) b0[i] = *(bf16x8*)&smem[20480 + (wn + i * 16 + rA) * 64 + cs0];

    for (int t = 0; t < 16; ++t) {
        const int cur = t & 1;
        unsigned short* sAc = smem + cur * 10240;
        unsigned short* sBc = smem + 20480 + cur * 8192;
        unsigned short* sAn = smem + (cur ^ 1) * 10240;
        unsigned short* sBn = smem + 20480 + (cur ^ 1) * 8192;

        // issue F1 = (t, ks1) reads; MFMA(F0) overlaps their latency
        bf16x8 a1[5], b1[4];
#pragma unroll
        for (int i = 0; i < 5; ++i) a1[i] = *(bf16x8*)&sAc[(wm + i * 16 + rA) * 64 + cs1];
#pragma unroll
        for (int i = 0; i < 4; ++i) b1[i] = *(bf16x8*)&sBc[(wn + i * 16 + rA) * 64 + cs1];
        __builtin_amdgcn_s_setprio(1);
#pragma unroll
        for (int mi = 0; mi < 5; ++mi)
#pragma unroll
            for (int ni = 0; ni < 4; ++ni)
                acc[mi][ni] = __builtin_amdgcn_mfma_f32_16x16x32_bf16(b0[ni], a0[mi], acc[mi][ni], 0, 0, 0);
        __builtin_amdgcn_s_setprio(0);

        // drain this wave's reads of buf[cur], then free it for re-staging
        asm volatile("s_waitcnt lgkmcnt(0)" ::: "memory");
        __builtin_amdgcn_sched_barrier(0);
        __builtin_amdgcn_s_barrier();
        __builtin_amdgcn_sched_barrier(0);

        if (t < 14) {
            const int ko = (t + 2) * 64;
#pragma unroll
            for (int p = 0; p < 5; ++p)
                async_copy16(xbf + a_off[p] + ko, &sAc[(p * 32 + ldsrow) * 64]);
#pragma unroll
            for (int p = 0; p < 4; ++p)
                async_copy16(WeT + b_off[p] + ko, &sBc[(p * 32 + ldsrow) * 64]);
        }
        if (t < 15) {
            if (t < 14) {
                asm volatile("s_waitcnt vmcnt(9)" ::: "memory");  // t+1 landed; t+2 in flight
            } else {
                asm volatile("s_waitcnt vmcnt(0)" ::: "memory");  // tile 15 landed
            }
            __builtin_amdgcn_sched_barrier(0);
            __builtin_amdgcn_s_barrier();
            __builtin_amdgcn_sched_barrier(0);
            // issue F0' = (t+1, ks0) reads; MFMA(F1) below overlaps their latency
#pragma unroll
            for (int i = 0; i < 5; ++i) a0[i] = *(bf16x8*)&sAn[(wm + i * 16 + rA) * 64 + cs0];
#pragma unroll
            for (int i = 0; i < 4; ++i) b0[i] = *(bf16x8*)&sBn[(wn + i * 16 + rA) * 64 + cs0];
        }

        __builtin_amdgcn_s_setprio(1);
#pragma unroll
        for (int mi = 0; mi < 5; ++mi)
#pragma unroll
            for (int ni = 0; ni < 4; ++ni)
                acc[mi][ni] = __builtin_amdgcn_mfma_f32_16x16x32_bf16(b1[ni], a1[mi], acc[mi][ni], 0, 0, 0);
        __builtin_amdgcn_s_setprio(0);
    }

    // epilogue: swapped-operand D layout -> lane (quad,rA) holds rows wm+mi*16+rA,
    // cols wn+ni*16+quad*4 .. +3 (consecutive) -> 8B uint2 stores, L2-mergeable.
    float4 bv[4];
#pragma unroll
    for (int ni = 0; ni < 4; ++ni)
        bv[ni] = *(const float4*)&be[(e << 10) + n0 + wn + ni * 16 + quad * 4];
#pragma unroll
    for (int mi = 0; mi < 5; ++mi) {
        const int lrow = wm + mi * 16 + rA;
        if (r0 + lrow < cnt) {
            unsigned short* yrow =
                ybuf + (((size_t)(e * N_TOK + r0 + lrow)) << 10) + n0 + wn + quad * 4;
#pragma unroll
            for (int ni = 0; ni < 4; ++ni) {
                uint2 pk;
                pk.x = f2bf(acc[mi][ni][0] + bv[ni].x) | (f2bf(acc[mi][ni][1] + bv[ni].y) << 16);
                pk.y = f2bf(acc[mi][ni][2] + bv[ni].z) | (f2bf(acc[mi][ni][3] + bv[ni].w) << 16);
                *(uint2*)&yrow[ni * 16] = pk;
            }
        }
    }
}

// ---------------- combine: out[t] = ga*yA[t] + gb*yB[t] ----------------
__global__ __launch_bounds__(256) void combine_kernel(const unsigned short* __restrict__ ybuf,
                                                      const int* __restrict__ slotA,
                                                      const int* __restrict__ slotB,
                                                      const float* __restrict__ ga,
                                                      const float* __restrict__ gb,
                                                      float* __restrict__ out) {
    const int wave = threadIdx.x >> 6, lane = threadIdx.x & 63;
    const int t = blockIdx.x * 4 + wave;
    const unsigned short* ra = ybuf + ((size_t)slotA[t] << 10);
    const unsigned short* rb = ybuf + ((size_t)slotB[t] << 10);
    const float a = ga[t], b = gb[t];
    float* orow = out + ((size_t)t << 10);
#pragma unroll
    for (int i = 0; i < 2; ++i) {
        int c = i * 512 + lane * 8;
        uint4 ua = *(const uint4*)&ra[c];
        uint4 ub = *(const uint4*)&rb[c];
        float4 o0, o1;
        o0.x = a * bflo(ua.x) + b * bflo(ub.x);
        o0.y = a * bfhi(ua.x) + b * bfhi(ub.x);
        o0.z = a * bflo(ua.y) + b * bflo(ub.y);
        o0.w = a * bfhi(ua.y) + b * bfhi(ub.y);
        o1.x = a * bflo(ua.z) + b * bflo(ub.z);
        o1.y = a * bfhi(ua.z) + b * bfhi(ub.z);
        o1.z = a * bflo(ua.w) + b * bflo(ub.w);
        o1.w = a * bfhi(ua.w) + b * bfhi(ub.w);
        *(float4*)&orow[c] = o0;
        *(float4*)&orow[c + 4] = o1;
    }
}

extern "C" void kernel_launch(void* const* d_in, const int* in_sizes, int n_in,
                              void* d_out, int out_size, void* d_ws, size_t ws_size,
                              hipStream_t stream) {
    const float* x  = (const float*)d_in[0];
    const float* We = (const float*)d_in[1];
    const float* be = (const float*)d_in[2];
    const float* Wg = (const float*)d_in[3];
    const float* bg = (const float*)d_in[4];
    float* out = (float*)d_out;

    char* ws = (char*)d_ws;
    size_t off = 0;
    int* counts = (int*)(ws + off); off += 8 * 32 * 4;            // 1 KB, padded 128 B/counter
    int* btok   = (int*)(ws + off); off += NEXP * N_TOK * 4;      // 256 KB
    int* slotA  = (int*)(ws + off); off += N_TOK * 4;
    int* slotB  = (int*)(ws + off); off += N_TOK * 4;
    int* ea = (int*)(ws + off); off += N_TOK * 4;
    int* eb = (int*)(ws + off); off += N_TOK * 4;
    float* ga = (float*)(ws + off); off += N_TOK * 4;
    float* gb = (float*)(ws + off); off += N_TOK * 4;
    unsigned short* WeT  = (unsigned short*)(ws + off); off += (size_t)NEXP * DDIM * ODIM * 2;  // 16.78 MB
    unsigned short* xbf  = (unsigned short*)(ws + off); off += (size_t)N_TOK * DDIM * 2;        // 16.78 MB
    unsigned short* ybuf = (unsigned short*)(ws + off); off += (size_t)NEXP * N_TOK * ODIM * 2; // 33.55 MB (slot-sparse)

    prep_kernel<<<dim3(4096), 256, 0, stream>>>(x, Wg, bg, We, ea, eb, ga, gb, xbf, WeT, counts);
    scatter_kernel<<<dim3(N_TOK / 64), 64, 0, stream>>>(ea, eb, counts, btok, slotA, slotB);
    moe_gemm<<<dim3(64 * 8 * 8), 256, 0, stream>>>(xbf, WeT, be, counts, btok, ybuf);
    combine_kernel<<<dim3(N_TOK / 4), 256, 0, stream>>>(ybuf, slotA, slotB, ga, gb, out);
}